// Round 7
// baseline (2272.136 us; speedup 1.0000x reference)
//
#include <hip/hip_runtime.h>
#include <hip/hip_bf16.h>

typedef _Float16 f16;
typedef __attribute__((ext_vector_type(8))) _Float16 f16x8;  // MFMA A/B frag
typedef __attribute__((ext_vector_type(4))) float f4v;       // 16x16 acc
typedef __attribute__((ext_vector_type(16))) float f32x16;   // 32x32 acc

constexpr int NSEQ = 4096;
constexpr int EMB  = 1024;
constexpr int NH   = 16;
constexpr int HD   = 32;       // head dim
constexpr int NL   = 6;
constexpr int HV   = NH * HD;  // 512
constexpr int FF   = 2 * EMB;  // 2048
constexpr int QKVW = 3 * HV;   // 1536 (q|k|v concatenated per row)
constexpr int KSEG = NSEQ / 2; // keys per split-K segment

// direct global->LDS DMA, 16B per lane (dest = uniform base + lane*16)
#define GLDS16(gp, lp) __builtin_amdgcn_global_load_lds( \
    (const __attribute__((address_space(1))) void*)(const void*)(gp), \
    (__attribute__((address_space(3))) void*)(void*)(lp), 16, 0, 0)

// pack two f32 -> 2xf16 (RTZ) as a dword
__device__ __forceinline__ unsigned pk2h(float a, float b) {
  auto h = __builtin_amdgcn_cvt_pkrtz(a, b);   // __fp16 ext_vector(2)
  unsigned d; __builtin_memcpy(&d, &h, 4);
  return d;
}

// ---------------- embedding: z = table[ctx] + pos; also f16 copy ----------
__global__ __launch_bounds__(256) void embed_kernel(const int* __restrict__ ctx,
    const float* __restrict__ table, const float* __restrict__ pos,
    float* __restrict__ z, f16* __restrict__ zh){
  int t = blockIdx.x * 256 + threadIdx.x;
  int n = t >> 8;
  int e = (t & 255) << 2;
  float4 a = *reinterpret_cast<const float4*>(table + (size_t)ctx[n] * EMB + e);
  float4 b = *reinterpret_cast<const float4*>(pos   + (size_t)n * EMB + e);
  float4 r = {a.x + b.x, a.y + b.y, a.z + b.z, a.w + b.w};
  *reinterpret_cast<float4*>(z + (size_t)n * EMB + e) = r;
  f16 o[4] = {(f16)r.x, (f16)r.y, (f16)r.z, (f16)r.w};
  uint2 u; __builtin_memcpy(&u, o, 8);
  *reinterpret_cast<uint2*>(zh + (size_t)n * EMB + e) = u;
}

// ------------- transpose-convert: out[n*K + k] = (f16)in[k*N + n] ----------
__global__ __launch_bounds__(256) void convT_kernel(const float* __restrict__ in,
    f16* __restrict__ out, int K, int N, long sInZ, long sOutZ){
  __shared__ float t[32][33];
  in  += (size_t)blockIdx.z * sInZ;
  out += (size_t)blockIdx.z * sOutZ;
  int k0 = blockIdx.x * 32, n0 = blockIdx.y * 32;
  int r = threadIdx.x >> 5, c = threadIdx.x & 31;
  #pragma unroll
  for (int i = 0; i < 4; i++)
    t[r + i*8][c] = in[(size_t)(k0 + r + i*8) * N + n0 + c];
  __syncthreads();
  #pragma unroll
  for (int i = 0; i < 4; i++)
    out[(size_t)(n0 + r + i*8) * K + k0 + c] = (f16)t[c][r + i*8];
}

// ---- fused q/k/v weight transpose: 3 sections x 16 heads in one launch ----
__global__ __launch_bounds__(256) void convT3_kernel(const float* __restrict__ wq,
    const float* __restrict__ wk, const float* __restrict__ wv,
    f16* __restrict__ out){
  __shared__ float t[32][33];
  int zz = blockIdx.z; int sec = zz >> 4, hh = zz & 15;
  const float* in = (sec == 0 ? wq : sec == 1 ? wk : wv) + (size_t)hh * EMB * HD;
  f16* o = out + (size_t)sec * HV * EMB + (size_t)hh * HD * EMB;
  int k0 = blockIdx.x * 32;
  int r = threadIdx.x >> 5, c = threadIdx.x & 31;
  #pragma unroll
  for (int i = 0; i < 4; i++)
    t[r + i*8][c] = in[(size_t)(k0 + r + i*8) * HD + c];
  __syncthreads();
  #pragma unroll
  for (int i = 0; i < 4; i++)
    o[(size_t)(r + i*8) * EMB + k0 + c] = (f16)t[c][r + i*8];
}

// ---------------- MFMA GEMM: C = act(A @ Bt^T + bias) + res ----------------
// A: f16 [M x K] row-major. Bt: f16 [N x K] row-major (B transposed).
// 128x128 tile, BK=32, 4 waves (2x2 of 64x64). 16x16x32 f16 MFMA.
// Staging: global_load_lds width=16, linear [128][32] LDS.
template<typename CT>
__global__ __launch_bounds__(256) void gemm_mfma(
    const f16* __restrict__ A, const f16* __restrict__ Bt, CT* C,
    const float* __restrict__ bias, const float* res,
    int K, int Nc, int leaky)
{
  __shared__ f16 Ash[128 * 32];
  __shared__ f16 Bsh[128 * 32];
  int tid = threadIdx.x;
  int lane = tid & 63, w = tid >> 6;
  int wm = w & 1, wn = w >> 1;
  int l16 = lane & 15, quad = lane >> 4;
  int row0 = blockIdx.y * 128, col0 = blockIdx.x * 128;

  f4v acc[4][4];
  #pragma unroll
  for (int i = 0; i < 4; i++)
    #pragma unroll
    for (int j = 0; j < 4; j++) acc[i][j] = {0.f, 0.f, 0.f, 0.f};

  int srow = lane >> 2;          // 0..15
  int scol = (lane & 3) * 8;     // 0/8/16/24
  const f16* gA0 = A  + (size_t)(row0 + w*32      + srow) * K + scol;
  const f16* gA1 = A  + (size_t)(row0 + w*32 + 16 + srow) * K + scol;
  const f16* gB0 = Bt + (size_t)(col0 + w*32      + srow) * K + scol;
  const f16* gB1 = Bt + (size_t)(col0 + w*32 + 16 + srow) * K + scol;
  f16* lA0 = Ash + (w*2    ) * 512;
  f16* lA1 = Ash + (w*2 + 1) * 512;
  f16* lB0 = Bsh + (w*2    ) * 512;
  f16* lB1 = Bsh + (w*2 + 1) * 512;

  for (int k0 = 0; k0 < K; k0 += 32) {
    __syncthreads();                       // prior tile fully consumed
    GLDS16(gA0 + k0, lA0);
    GLDS16(gA1 + k0, lA1);
    GLDS16(gB0 + k0, lB0);
    GLDS16(gB1 + k0, lB1);
    __syncthreads();                       // vmcnt(0) drain: tile resident
    f16x8 af[4], bf[4];
    #pragma unroll
    for (int mt = 0; mt < 4; mt++)
      af[mt] = *reinterpret_cast<const f16x8*>(&Ash[(wm*64 + mt*16 + l16) * 32 + quad*8]);
    #pragma unroll
    for (int nt = 0; nt < 4; nt++)
      bf[nt] = *reinterpret_cast<const f16x8*>(&Bsh[(wn*64 + nt*16 + l16) * 32 + quad*8]);
    #pragma unroll
    for (int mt = 0; mt < 4; mt++)
      #pragma unroll
      for (int nt = 0; nt < 4; nt++)
        acc[mt][nt] = __builtin_amdgcn_mfma_f32_16x16x32_f16(af[mt], bf[nt], acc[mt][nt], 0, 0, 0);
  }

  #pragma unroll
  for (int mt = 0; mt < 4; mt++) {
    #pragma unroll
    for (int nt = 0; nt < 4; nt++) {
      int ccol = col0 + wn*64 + nt*16 + l16;
      float bv = bias ? bias[ccol] : 0.f;
      #pragma unroll
      for (int reg = 0; reg < 4; reg++) {
        int crow = row0 + wm*64 + mt*16 + quad*4 + reg;
        float v = acc[mt][nt][reg] + bv;
        if (leaky) v = v > 0.f ? v : 0.01f * v;
        if (res)   v += res[(size_t)crow * Nc + ccol];
        if constexpr (sizeof(CT) == 2) C[(size_t)crow * Nc + ccol] = (f16)v;
        else                           C[(size_t)crow * Nc + ccol] = v;
      }
    }
  }
}

// ---------------- MFMA flash attention, 32x32, split-K ----------------------
// Block = 256 thr = 4 waves x 32 queries = 128 q. blockIdx.z = key segment.
// Writes UNNORMALIZED partial O (f32) + (m, l) per (z, query, head).
// S^T chunk layout / register-P half-exchange identical to R5 (verified).
__global__ __launch_bounds__(256, 4) void attn_mfma(const f16* __restrict__ qkv,
    float* __restrict__ Opart, float2* __restrict__ ml)
{
  __shared__ f16 Ks[2][128][40];   // [key][dim]  stride 80B
  __shared__ f16 Vt[2][32][136];   // [dim][key]  stride 272B
  int tid = threadIdx.x;
  int lane = tid & 63, w = tid >> 6;       // 4 waves
  int l31 = lane & 31, h = lane >> 5;
  int hd = blockIdx.y;
  int zseg = blockIdx.z;
  int q0 = blockIdx.x * 128 + w * 32;
  int base = zseg * KSEG;
  const float sc = 0.17677669529663687f * 1.4426950408889634f; // 1/sqrt(32)*log2e

  // Q B-frags: qf{0,1}[j] = Q[q0+l31][sub*16 + h*8 + j] * sc
  f16x8 qf0, qf1;
  {
    const f16* qp = qkv + (size_t)(q0 + l31) * QKVW + hd * HD + h * 8;
    union { uint4 u; f16 e[8]; } a, b;
    a.u = *reinterpret_cast<const uint4*>(qp);
    b.u = *reinterpret_cast<const uint4*>(qp + 16);
    #pragma unroll
    for (int i = 0; i < 8; i++) {
      a.e[i] = (f16)((float)a.e[i] * sc);
      b.e[i] = (f16)((float)b.e[i] * sc);
    }
    __builtin_memcpy(&qf0, a.e, 16);
    __builtin_memcpy(&qf1, b.e, 16);
  }

  float m_ = -1e30f, lsum = 0.f;           // per-lane state for query l31
  f32x16 oaccA, oaccB, zz;
  #pragma unroll
  for (int i = 0; i < 16; i++) { oaccA[i] = 0.f; oaccB[i] = 0.f; zz[i] = 0.f; }

  // staging: K: 2 x uint4 per thread; V: 2 key rows x 8 dims per thread
  int krow = tid >> 1, kcol = (tid & 1) * 16;
  int vkp = tid & 63, vdg = tid >> 6;
  uint4 kr0, kr1, vr0, vr1;

  auto LOADT = [&](int kt) {               // issue global loads (reg staging)
    const f16* kp = qkv + (size_t)(kt + krow) * QKVW + HV + hd * HD + kcol;
    kr0 = *reinterpret_cast<const uint4*>(kp);
    kr1 = *reinterpret_cast<const uint4*>(kp + 8);
    const f16* vp = qkv + (size_t)(kt + 2*vkp) * QKVW + 2*HV + hd * HD + vdg * 8;
    vr0 = *reinterpret_cast<const uint4*>(vp);
    vr1 = *reinterpret_cast<const uint4*>(vp + QKVW);
  };
  auto WRITET = [&](int b) {               // regs -> LDS (vmcnt wait here)
    *reinterpret_cast<uint4*>(&Ks[b][krow][kcol])     = kr0;
    *reinterpret_cast<uint4*>(&Ks[b][krow][kcol + 8]) = kr1;
    union { uint4 u; f16 e[8]; } c0, c1;
    c0.u = vr0; c1.u = vr1;
    #pragma unroll
    for (int i = 0; i < 8; i++) {          // pack key pair -> one dword
      f16 pr[2] = {c0.e[i], c1.e[i]};
      unsigned d; __builtin_memcpy(&d, pr, 4);
      *reinterpret_cast<unsigned*>(&Vt[b][vdg * 8 + i][2 * vkp]) = d;
    }
  };

  LOADT(base);
  WRITET(0);
  __syncthreads();
  int cur = 0;

  for (int kt = base; kt < base + KSEG; kt += 128) {
    LOADT(base + ((kt + 128 - base) & (KSEG - 1)));   // issue next tile (T14)

    // ---- S^T: 4 chunks x 2 serial MFMA ----
    f32x16 s0, s1, s2, s3;
    __builtin_amdgcn_s_setprio(1);
    #define SCHUNK(sv, c) { \
      f16x8 a0 = *reinterpret_cast<const f16x8*>(&Ks[cur][(c)*32 + l31][h*8]); \
      f16x8 a1 = *reinterpret_cast<const f16x8*>(&Ks[cur][(c)*32 + l31][16 + h*8]); \
      sv = __builtin_amdgcn_mfma_f32_32x32x16_f16(a0, qf0, zz, 0, 0, 0); \
      sv = __builtin_amdgcn_mfma_f32_32x32x16_f16(a1, qf1, sv, 0, 0, 0); }
    SCHUNK(s0, 0) SCHUNK(s1, 1) SCHUNK(s2, 2) SCHUNK(s3, 3)
    #undef SCHUNK
    __builtin_amdgcn_s_setprio(0);

    // ---- tile max: per-chunk trees + cross-half (1 shfl) ----
    auto cmax = [](const f32x16& s) {
      float a = fmaxf(fmaxf(s[0], s[1]),   fmaxf(s[2], s[3]));
      float b = fmaxf(fmaxf(s[4], s[5]),   fmaxf(s[6], s[7]));
      float c = fmaxf(fmaxf(s[8], s[9]),   fmaxf(s[10], s[11]));
      float d = fmaxf(fmaxf(s[12], s[13]), fmaxf(s[14], s[15]));
      return fmaxf(fmaxf(a, b), fmaxf(c, d));
    };
    float tm = fmaxf(fmaxf(cmax(s0), cmax(s1)), fmaxf(cmax(s2), cmax(s3)));
    tm = fmaxf(tm, __shfl_xor(tm, 32));
    if (!__all(tm <= m_)) {                // defer-max: skip is bit-exact
      float mN = fmaxf(m_, tm);
      float corr = __builtin_amdgcn_exp2f(m_ - mN);   // first tile: 0
      m_ = mN; lsum *= corr;
      #pragma unroll
      for (int i = 0; i < 16; i++) { oaccA[i] *= corr; oaccB[i] *= corr; }
    }

    // ---- per chunk: exp2, pack, half-exchange, PV MFMA ----
    float ls = 0.f;
    #define PVCHUNK(sv, c, oacc) { \
      float pv[16]; \
      _Pragma("unroll") \
      for (int r_ = 0; r_ < 16; r_++) { \
        pv[r_] = __builtin_amdgcn_exp2f(sv[r_] - m_); ls += pv[r_]; } \
      unsigned d00 = pk2h(pv[0],  pv[1]),  d01 = pk2h(pv[2],  pv[3]);  \
      unsigned d10 = pk2h(pv[4],  pv[5]),  d11 = pk2h(pv[6],  pv[7]);  \
      unsigned d20 = pk2h(pv[8],  pv[9]),  d21 = pk2h(pv[10], pv[11]); \
      unsigned d30 = pk2h(pv[12], pv[13]), d31 = pk2h(pv[14], pv[15]); \
      unsigned rxA0 = (unsigned)__shfl_xor((int)(h ? d00 : d10), 32); \
      unsigned rxA1 = (unsigned)__shfl_xor((int)(h ? d01 : d11), 32); \
      unsigned rxB0 = (unsigned)__shfl_xor((int)(h ? d20 : d30), 32); \
      unsigned rxB1 = (unsigned)__shfl_xor((int)(h ? d21 : d31), 32); \
      unsigned o00 = h ? d10 : d00, o01 = h ? d11 : d01; \
      unsigned o10 = h ? d30 : d20, o11 = h ? d31 : d21; \
      unsigned fr0[4] = { h ? rxA0 : o00, h ? rxA1 : o01, \
                          h ? o00 : rxA0, h ? o01 : rxA1 }; \
      unsigned fr1[4] = { h ? rxB0 : o10, h ? rxB1 : o11, \
                          h ? o10 : rxB0, h ? o11 : rxB1 }; \
      f16x8 pb0, pb1; \
      __builtin_memcpy(&pb0, fr0, 16); __builtin_memcpy(&pb1, fr1, 16); \
      f16x8 vf0 = *reinterpret_cast<const f16x8*>(&Vt[cur][l31][(c)*32 + h*8]); \
      f16x8 vf1 = *reinterpret_cast<const f16x8*>(&Vt[cur][l31][(c)*32 + 16 + h*8]); \
      __builtin_amdgcn_s_setprio(1); \
      oacc = __builtin_amdgcn_mfma_f32_32x32x16_f16(vf0, pb0, oacc, 0, 0, 0); \
      oacc = __builtin_amdgcn_mfma_f32_32x32x16_f16(vf1, pb1, oacc, 0, 0, 0); \
      __builtin_amdgcn_s_setprio(0); }
    PVCHUNK(s0, 0, oaccA)
    PVCHUNK(s1, 1, oaccB)
    PVCHUNK(s2, 2, oaccA)
    PVCHUNK(s3, 3, oaccB)
    #undef PVCHUNK
    lsum += ls;

    if (kt + 128 < base + KSEG) WRITET(cur ^ 1);  // vmcnt hidden by compute
    __syncthreads();
    cur ^= 1;
  }

  // epilogue: UNNORMALIZED partial O + (m, l)
  float lt = lsum + __shfl_xor(lsum, 32);
  float* op = Opart + (((size_t)zseg * NSEQ + q0 + l31) * NH + hd) * HD;
  #pragma unroll
  for (int g = 0; g < 4; g++) {            // dims 8g+4h+{0..3}
    float4 v4 = {oaccA[4*g+0] + oaccB[4*g+0], oaccA[4*g+1] + oaccB[4*g+1],
                 oaccA[4*g+2] + oaccB[4*g+2], oaccA[4*g+3] + oaccB[4*g+3]};
    *reinterpret_cast<float4*>(op + 8*g + 4*h) = v4;
  }
  if (h == 0)
    ml[((size_t)zseg * NSEQ + q0 + l31) * NH + hd] = make_float2(m_, lt);
}

// ---------------- split-K merge: Oh = norm(sum of partials) ----------------
__global__ __launch_bounds__(256) void attn_merge(const float* __restrict__ Opart,
    const float2* __restrict__ ml, f16* __restrict__ Oh){
  int t = blockIdx.x * 256 + threadIdx.x;  // NSEQ*NH*HD/4 threads
  int n = t >> 7;                          // 128 = NH*HD/4
  int rem = t & 127;
  int h = rem >> 3, dg = rem & 7;
  float2 a = ml[((size_t)0 * NSEQ + n) * NH + h];
  float2 b = ml[((size_t)1 * NSEQ + n) * NH + h];
  float m = fmaxf(a.x, b.x);
  float c0 = __builtin_amdgcn_exp2f(a.x - m);
  float c1 = __builtin_amdgcn_exp2f(b.x - m);
  float inv = 1.f / (c0 * a.y + c1 * b.y);
  float4 o0 = *reinterpret_cast<const float4*>(
      &Opart[(((size_t)0 * NSEQ + n) * NH + h) * HD + dg * 4]);
  float4 o1 = *reinterpret_cast<const float4*>(
      &Opart[(((size_t)1 * NSEQ + n) * NH + h) * HD + dg * 4]);
  f16 ob[4] = {(f16)((c0*o0.x + c1*o1.x) * inv), (f16)((c0*o0.y + c1*o1.y) * inv),
               (f16)((c0*o0.z + c1*o1.z) * inv), (f16)((c0*o0.w + c1*o1.w) * inv)};
  uint2 u; __builtin_memcpy(&u, ob, 8);
  *reinterpret_cast<uint2*>(Oh + (size_t)n * HV + h * HD + dg * 4) = u;
}

// ------------- layernorm (dim 1, ddof=1, no eps) + f16 copy ----------------
__global__ __launch_bounds__(256) void ln_kernel(const float* in, float* out,
                                                 f16* __restrict__ outh){
  __shared__ float sm[8];
  int row = blockIdx.x, tid = threadIdx.x;
  float4 x = reinterpret_cast<const float4*>(in + (size_t)row * EMB)[tid];
  float s = x.x + x.y + x.z + x.w;
  #pragma unroll
  for (int o = 32; o > 0; o >>= 1) s += __shfl_down(s, o);
  int wid = tid >> 6, lane = tid & 63;
  if (lane == 0) sm[wid] = s;
  __syncthreads();
  float mean = (sm[0] + sm[1] + sm[2] + sm[3]) * (1.f / EMB);
  float dx = x.x - mean, dy = x.y - mean, dz = x.z - mean, dw = x.w - mean;
  float qs = dx*dx + dy*dy + dz*dz + dw*dw;
  #pragma unroll
  for (int o = 32; o > 0; o >>= 1) qs += __shfl_down(qs, o);
  if (lane == 0) sm[4 + wid] = qs;
  __syncthreads();
  float var = (sm[4] + sm[5] + sm[6] + sm[7]) * (1.f / (EMB - 1));
  float inv = rsqrtf(var);
  float4 y = {dx * inv, dy * inv, dz * inv, dw * inv};
  reinterpret_cast<float4*>(out + (size_t)row * EMB)[tid] = y;
  f16 o4[4] = {(f16)y.x, (f16)y.y, (f16)y.z, (f16)y.w};
  uint2 u; __builtin_memcpy(&u, o4, 8);
  reinterpret_cast<uint2*>(outh + (size_t)row * EMB)[tid] = u;
}

extern "C" void kernel_launch(void* const* d_in, const int* in_sizes, int n_in,
                              void* d_out, int out_size, void* d_ws, size_t ws_size,
                              hipStream_t stream)
{
  const int*   ctx   = (const int*)d_in[0];
  const float* table = (const float*)d_in[1];
  const float* pos   = (const float*)d_in[2];
  const float* Wq    = (const float*)d_in[3];
  const float* Wk    = (const float*)d_in[4];
  const float* Wv    = (const float*)d_in[5];
  const float* Wo    = (const float*)d_in[6];
  const float* W1    = (const float*)d_in[7];
  const float* b1    = (const float*)d_in[8];
  const float* W2    = (const float*)d_in[9];
  const float* b2    = (const float*)d_in[10];

  float* z = (float*)d_out;                 // residual stream f32 [N][E]

  char* ws = (char*)d_ws;
  const size_t MB = 1u << 20;
  // ws layout (52 MB):
  //  [0,16)   an    f32 [N][E]      } Opart f32 [2][N][H][32] = 16MB aliases
  //  [16,24)  anh   f16 [N][E]      } [0,16); ml [16,17). Both dead during
  //  [24,32)  zh    f16 [N][E]        the attention window (an/anh written
  //  [32,44)  qkvh  f16 [N][1536]     by ln AFTER Wo-GEMM).
  //  [44,48)  Oh    f16 [N][512]
  //  [48,52)  wbuf  f16
  float*  an    = (float*)(ws);
  f16*    anh   = (f16*)  (ws + 16 * MB);
  f16*    zh    = (f16*)  (ws + 24 * MB);
  f16*    qkvh  = (f16*)  (ws + 32 * MB);
  f16*    Oh    = (f16*)  (ws + 44 * MB);
  f16*    h1h   = (f16*)  (ws + 32 * MB);
  f16*    wbuf  = (f16*)  (ws + 48 * MB);
  float*  Opart = (float*)(ws);
  float2* mlb   = (float2*)(ws + 16 * MB);

  embed_kernel<<<NSEQ * EMB / 4 / 256, 256, 0, stream>>>(ctx, table, pos, z, zh);

  for (int l = 0; l < NL; l++) {
    const float* wq  = Wq + (size_t)l * NH * EMB * HD;
    const float* wk  = Wk + (size_t)l * NH * EMB * HD;
    const float* wv  = Wv + (size_t)l * NH * EMB * HD;
    const float* wo  = Wo + (size_t)l * HV * EMB;
    const float* w1  = W1 + (size_t)l * EMB * FF;
    const float* bb1 = b1 + (size_t)l * FF;
    const float* w2  = W2 + (size_t)l * FF * EMB;
    const float* bb2 = b2 + (size_t)l * EMB;

    // qkvT rows: [0,512)=Q, [512,1024)=K, [1024,1536)=V (fused 3-in-1)
    convT3_kernel<<<dim3(EMB/32, 1, 48), 256, 0, stream>>>(wq, wk, wv, wbuf);
    gemm_mfma<f16><<<dim3(QKVW/128, NSEQ/128), 256, 0, stream>>>(
        zh, wbuf, qkvh, nullptr, nullptr, EMB, QKVW, 0);

    attn_mfma<<<dim3(NSEQ/128, NH, 2), 256, 0, stream>>>(qkvh, Opart, mlb);
    attn_merge<<<NSEQ * NH * HD / 4 / 256, 256, 0, stream>>>(Opart, mlb, Oh);

    // z += Oh @ Wo : WoT [1024][512]
    convT_kernel<<<dim3(HV/32, EMB/32, 1), 256, 0, stream>>>(
        wo, wbuf, HV, EMB, 0, 0);
    gemm_mfma<float><<<dim3(EMB/128, NSEQ/128), 256, 0, stream>>>(
        Oh, wbuf, z, nullptr, z, HV, EMB, 0);
    ln_kernel<<<NSEQ, 256, 0, stream>>>(z, an, anh);

    // h1 = leaky(an @ W1 + b1) : W1T [2048][1024]
    convT_kernel<<<dim3(EMB/32, FF/32, 1), 256, 0, stream>>>(
        w1, wbuf, EMB, FF, 0, 0);
    gemm_mfma<f16><<<dim3(FF/128, NSEQ/128), 256, 0, stream>>>(
        anh, wbuf, h1h, bb1, nullptr, EMB, FF, 1);
    // z = h1 @ W2 + b2 + an : W2T [1024][2048]
    convT_kernel<<<dim3(FF/32, EMB/32, 1), 256, 0, stream>>>(
        w2, wbuf, FF, EMB, 0, 0);
    gemm_mfma<float><<<dim3(EMB/128, NSEQ/128), 256, 0, stream>>>(
        h1h, wbuf, z, bb2, an, FF, EMB, 0);
    ln_kernel<<<NSEQ, 256, 0, stream>>>(z, z, zh);
  }
}

// Round 8
// 1931.050 us; speedup vs baseline: 1.1766x; 1.1766x over previous
//
#include <hip/hip_runtime.h>
#include <hip/hip_bf16.h>

typedef _Float16 f16;
typedef __attribute__((ext_vector_type(8))) _Float16 f16x8;  // MFMA A/B frag
typedef __attribute__((ext_vector_type(4))) float f4v;       // 16x16 acc
typedef __attribute__((ext_vector_type(16))) float f32x16;   // 32x32 acc

constexpr int NSEQ = 4096;
constexpr int EMB  = 1024;
constexpr int NH   = 16;
constexpr int HD   = 32;       // head dim
constexpr int NL   = 6;
constexpr int HV   = NH * HD;  // 512
constexpr int FF   = 2 * EMB;  // 2048
constexpr int QKVW = 3 * HV;   // 1536 (q|k|v concatenated per row)
constexpr int KSEG = NSEQ / 2; // keys per split-K segment

// direct global->LDS DMA, 16B per lane (dest = uniform base + lane*16)
#define GLDS16(gp, lp) __builtin_amdgcn_global_load_lds( \
    (const __attribute__((address_space(1))) void*)(const void*)(gp), \
    (__attribute__((address_space(3))) void*)(void*)(lp), 16, 0, 0)

// pack two f32 -> 2xf16 (RTZ) as a dword
__device__ __forceinline__ unsigned pk2h(float a, float b) {
  auto h = __builtin_amdgcn_cvt_pkrtz(a, b);   // __fp16 ext_vector(2)
  unsigned d; __builtin_memcpy(&d, &h, 4);
  return d;
}

// ---------------- embedding: z = table[ctx] + pos; also f16 copy ----------
__global__ __launch_bounds__(256) void embed_kernel(const int* __restrict__ ctx,
    const float* __restrict__ table, const float* __restrict__ pos,
    float* __restrict__ z, f16* __restrict__ zh){
  int t = blockIdx.x * 256 + threadIdx.x;
  int n = t >> 8;
  int e = (t & 255) << 2;
  float4 a = *reinterpret_cast<const float4*>(table + (size_t)ctx[n] * EMB + e);
  float4 b = *reinterpret_cast<const float4*>(pos   + (size_t)n * EMB + e);
  float4 r = {a.x + b.x, a.y + b.y, a.z + b.z, a.w + b.w};
  *reinterpret_cast<float4*>(z + (size_t)n * EMB + e) = r;
  f16 o[4] = {(f16)r.x, (f16)r.y, (f16)r.z, (f16)r.w};
  uint2 u; __builtin_memcpy(&u, o, 8);
  *reinterpret_cast<uint2*>(zh + (size_t)n * EMB + e) = u;
}

// ------------- transpose-convert: out[n*K + k] = (f16)in[k*N + n] ----------
__global__ __launch_bounds__(256) void convT_kernel(const float* __restrict__ in,
    f16* __restrict__ out, int K, int N, long sInZ, long sOutZ){
  __shared__ float t[32][33];
  in  += (size_t)blockIdx.z * sInZ;
  out += (size_t)blockIdx.z * sOutZ;
  int k0 = blockIdx.x * 32, n0 = blockIdx.y * 32;
  int r = threadIdx.x >> 5, c = threadIdx.x & 31;
  #pragma unroll
  for (int i = 0; i < 4; i++)
    t[r + i*8][c] = in[(size_t)(k0 + r + i*8) * N + n0 + c];
  __syncthreads();
  #pragma unroll
  for (int i = 0; i < 4; i++)
    out[(size_t)(n0 + r + i*8) * K + k0 + c] = (f16)t[c][r + i*8];
}

// ---- fused q/k/v weight transpose: 3 sections x 16 heads in one launch ----
__global__ __launch_bounds__(256) void convT3_kernel(const float* __restrict__ wq,
    const float* __restrict__ wk, const float* __restrict__ wv,
    f16* __restrict__ out){
  __shared__ float t[32][33];
  int zz = blockIdx.z; int sec = zz >> 4, hh = zz & 15;
  const float* in = (sec == 0 ? wq : sec == 1 ? wk : wv) + (size_t)hh * EMB * HD;
  f16* o = out + (size_t)sec * HV * EMB + (size_t)hh * HD * EMB;
  int k0 = blockIdx.x * 32;
  int r = threadIdx.x >> 5, c = threadIdx.x & 31;
  #pragma unroll
  for (int i = 0; i < 4; i++)
    t[r + i*8][c] = in[(size_t)(k0 + r + i*8) * HD + c];
  __syncthreads();
  #pragma unroll
  for (int i = 0; i < 4; i++)
    o[(size_t)(r + i*8) * EMB + k0 + c] = (f16)t[c][r + i*8];
}

// ---------------- MFMA GEMM: C = act(A @ Bt^T + bias) + res ----------------
// A: f16 [M x K] row-major. Bt: f16 [N x K] row-major (B transposed).
// 128x128 tile, BK=32, 4 waves (2x2 of 64x64). 16x16x32 f16 MFMA.
// Staging: global_load_lds width=16, linear [128][32] LDS.
template<typename CT>
__global__ __launch_bounds__(256) void gemm_mfma(
    const f16* __restrict__ A, const f16* __restrict__ Bt, CT* C,
    const float* __restrict__ bias, const float* res,
    int K, int Nc, int leaky)
{
  __shared__ f16 Ash[128 * 32];
  __shared__ f16 Bsh[128 * 32];
  int tid = threadIdx.x;
  int lane = tid & 63, w = tid >> 6;
  int wm = w & 1, wn = w >> 1;
  int l16 = lane & 15, quad = lane >> 4;
  int row0 = blockIdx.y * 128, col0 = blockIdx.x * 128;

  f4v acc[4][4];
  #pragma unroll
  for (int i = 0; i < 4; i++)
    #pragma unroll
    for (int j = 0; j < 4; j++) acc[i][j] = {0.f, 0.f, 0.f, 0.f};

  int srow = lane >> 2;          // 0..15
  int scol = (lane & 3) * 8;     // 0/8/16/24
  const f16* gA0 = A  + (size_t)(row0 + w*32      + srow) * K + scol;
  const f16* gA1 = A  + (size_t)(row0 + w*32 + 16 + srow) * K + scol;
  const f16* gB0 = Bt + (size_t)(col0 + w*32      + srow) * K + scol;
  const f16* gB1 = Bt + (size_t)(col0 + w*32 + 16 + srow) * K + scol;
  f16* lA0 = Ash + (w*2    ) * 512;
  f16* lA1 = Ash + (w*2 + 1) * 512;
  f16* lB0 = Bsh + (w*2    ) * 512;
  f16* lB1 = Bsh + (w*2 + 1) * 512;

  for (int k0 = 0; k0 < K; k0 += 32) {
    __syncthreads();                       // prior tile fully consumed
    GLDS16(gA0 + k0, lA0);
    GLDS16(gA1 + k0, lA1);
    GLDS16(gB0 + k0, lB0);
    GLDS16(gB1 + k0, lB1);
    __syncthreads();                       // vmcnt(0) drain: tile resident
    f16x8 af[4], bf[4];
    #pragma unroll
    for (int mt = 0; mt < 4; mt++)
      af[mt] = *reinterpret_cast<const f16x8*>(&Ash[(wm*64 + mt*16 + l16) * 32 + quad*8]);
    #pragma unroll
    for (int nt = 0; nt < 4; nt++)
      bf[nt] = *reinterpret_cast<const f16x8*>(&Bsh[(wn*64 + nt*16 + l16) * 32 + quad*8]);
    #pragma unroll
    for (int mt = 0; mt < 4; mt++)
      #pragma unroll
      for (int nt = 0; nt < 4; nt++)
        acc[mt][nt] = __builtin_amdgcn_mfma_f32_16x16x32_f16(af[mt], bf[nt], acc[mt][nt], 0, 0, 0);
  }

  #pragma unroll
  for (int mt = 0; mt < 4; mt++) {
    #pragma unroll
    for (int nt = 0; nt < 4; nt++) {
      int ccol = col0 + wn*64 + nt*16 + l16;
      float bv = bias ? bias[ccol] : 0.f;
      #pragma unroll
      for (int reg = 0; reg < 4; reg++) {
        int crow = row0 + wm*64 + mt*16 + quad*4 + reg;
        float v = acc[mt][nt][reg] + bv;
        if (leaky) v = v > 0.f ? v : 0.01f * v;
        if (res)   v += res[(size_t)crow * Nc + ccol];
        if constexpr (sizeof(CT) == 2) C[(size_t)crow * Nc + ccol] = (f16)v;
        else                           C[(size_t)crow * Nc + ccol] = v;
      }
    }
  }
}

// ---------------- MFMA flash attention, 32x32, split-K ----------------------
// Block = 256 thr = 4 waves x 32 queries = 128 q. blockIdx.z = key segment.
// Writes UNNORMALIZED partial O (f32) + (m, l) per (z, query, head).
// S^T chunk layout / register-P half-exchange identical to R5 (verified).
// NOTE: no min-waves hint — (256,4) forced VGPR 116->64 and spilled ~220MB
// scratch/dispatch (R7 counters). Natural 116 VGPR already gives 4 w/SIMD.
__global__ __launch_bounds__(256) void attn_mfma(const f16* __restrict__ qkv,
    float* __restrict__ Opart, float2* __restrict__ ml)
{
  __shared__ f16 Ks[2][128][40];   // [key][dim]  stride 80B
  __shared__ f16 Vt[2][32][136];   // [dim][key]  stride 272B
  int tid = threadIdx.x;
  int lane = tid & 63, w = tid >> 6;       // 4 waves
  int l31 = lane & 31, h = lane >> 5;
  int hd = blockIdx.y;
  int zseg = blockIdx.z;
  int q0 = blockIdx.x * 128 + w * 32;
  int base = zseg * KSEG;
  const float sc = 0.17677669529663687f * 1.4426950408889634f; // 1/sqrt(32)*log2e

  // Q B-frags: qf{0,1}[j] = Q[q0+l31][sub*16 + h*8 + j] * sc
  f16x8 qf0, qf1;
  {
    const f16* qp = qkv + (size_t)(q0 + l31) * QKVW + hd * HD + h * 8;
    union { uint4 u; f16 e[8]; } a, b;
    a.u = *reinterpret_cast<const uint4*>(qp);
    b.u = *reinterpret_cast<const uint4*>(qp + 16);
    #pragma unroll
    for (int i = 0; i < 8; i++) {
      a.e[i] = (f16)((float)a.e[i] * sc);
      b.e[i] = (f16)((float)b.e[i] * sc);
    }
    __builtin_memcpy(&qf0, a.e, 16);
    __builtin_memcpy(&qf1, b.e, 16);
  }

  float m_ = -1e30f, lsum = 0.f;           // per-lane state for query l31
  f32x16 oaccA, oaccB, zz;
  #pragma unroll
  for (int i = 0; i < 16; i++) { oaccA[i] = 0.f; oaccB[i] = 0.f; zz[i] = 0.f; }

  // staging: K: 2 x uint4 per thread; V: 2 key rows x 8 dims per thread
  int krow = tid >> 1, kcol = (tid & 1) * 16;
  int vkp = tid & 63, vdg = tid >> 6;
  uint4 kr0, kr1, vr0, vr1;

  auto LOADT = [&](int kt) {               // issue global loads (reg staging)
    const f16* kp = qkv + (size_t)(kt + krow) * QKVW + HV + hd * HD + kcol;
    kr0 = *reinterpret_cast<const uint4*>(kp);
    kr1 = *reinterpret_cast<const uint4*>(kp + 8);
    const f16* vp = qkv + (size_t)(kt + 2*vkp) * QKVW + 2*HV + hd * HD + vdg * 8;
    vr0 = *reinterpret_cast<const uint4*>(vp);
    vr1 = *reinterpret_cast<const uint4*>(vp + QKVW);
  };
  auto WRITET = [&](int b) {               // regs -> LDS (vmcnt wait here)
    *reinterpret_cast<uint4*>(&Ks[b][krow][kcol])     = kr0;
    *reinterpret_cast<uint4*>(&Ks[b][krow][kcol + 8]) = kr1;
    union { uint4 u; f16 e[8]; } c0, c1;
    c0.u = vr0; c1.u = vr1;
    #pragma unroll
    for (int i = 0; i < 8; i++) {          // pack key pair -> one dword
      f16 pr[2] = {c0.e[i], c1.e[i]};
      unsigned d; __builtin_memcpy(&d, pr, 4);
      *reinterpret_cast<unsigned*>(&Vt[b][vdg * 8 + i][2 * vkp]) = d;
    }
  };

  LOADT(base);
  WRITET(0);
  __syncthreads();
  int cur = 0;

  for (int kt = base; kt < base + KSEG; kt += 128) {
    LOADT(base + ((kt + 128 - base) & (KSEG - 1)));   // issue next tile (T14)

    // ---- S^T: 4 chunks x 2 serial MFMA ----
    f32x16 s0, s1, s2, s3;
    __builtin_amdgcn_s_setprio(1);
    #define SCHUNK(sv, c) { \
      f16x8 a0 = *reinterpret_cast<const f16x8*>(&Ks[cur][(c)*32 + l31][h*8]); \
      f16x8 a1 = *reinterpret_cast<const f16x8*>(&Ks[cur][(c)*32 + l31][16 + h*8]); \
      sv = __builtin_amdgcn_mfma_f32_32x32x16_f16(a0, qf0, zz, 0, 0, 0); \
      sv = __builtin_amdgcn_mfma_f32_32x32x16_f16(a1, qf1, sv, 0, 0, 0); }
    SCHUNK(s0, 0) SCHUNK(s1, 1) SCHUNK(s2, 2) SCHUNK(s3, 3)
    #undef SCHUNK
    __builtin_amdgcn_s_setprio(0);

    // ---- tile max: per-chunk trees + cross-half (1 shfl) ----
    auto cmax = [](const f32x16& s) {
      float a = fmaxf(fmaxf(s[0], s[1]),   fmaxf(s[2], s[3]));
      float b = fmaxf(fmaxf(s[4], s[5]),   fmaxf(s[6], s[7]));
      float c = fmaxf(fmaxf(s[8], s[9]),   fmaxf(s[10], s[11]));
      float d = fmaxf(fmaxf(s[12], s[13]), fmaxf(s[14], s[15]));
      return fmaxf(fmaxf(a, b), fmaxf(c, d));
    };
    float tm = fmaxf(fmaxf(cmax(s0), cmax(s1)), fmaxf(cmax(s2), cmax(s3)));
    tm = fmaxf(tm, __shfl_xor(tm, 32));
    if (!__all(tm <= m_)) {                // defer-max: skip is bit-exact
      float mN = fmaxf(m_, tm);
      float corr = __builtin_amdgcn_exp2f(m_ - mN);   // first tile: 0
      m_ = mN; lsum *= corr;
      #pragma unroll
      for (int i = 0; i < 16; i++) { oaccA[i] *= corr; oaccB[i] *= corr; }
    }

    // ---- per chunk: exp2, pack, half-exchange, PV MFMA ----
    float ls = 0.f;
    #define PVCHUNK(sv, c, oacc) { \
      float pv[16]; \
      _Pragma("unroll") \
      for (int r_ = 0; r_ < 16; r_++) { \
        pv[r_] = __builtin_amdgcn_exp2f(sv[r_] - m_); ls += pv[r_]; } \
      unsigned d00 = pk2h(pv[0],  pv[1]),  d01 = pk2h(pv[2],  pv[3]);  \
      unsigned d10 = pk2h(pv[4],  pv[5]),  d11 = pk2h(pv[6],  pv[7]);  \
      unsigned d20 = pk2h(pv[8],  pv[9]),  d21 = pk2h(pv[10], pv[11]); \
      unsigned d30 = pk2h(pv[12], pv[13]), d31 = pk2h(pv[14], pv[15]); \
      unsigned rxA0 = (unsigned)__shfl_xor((int)(h ? d00 : d10), 32); \
      unsigned rxA1 = (unsigned)__shfl_xor((int)(h ? d01 : d11), 32); \
      unsigned rxB0 = (unsigned)__shfl_xor((int)(h ? d20 : d30), 32); \
      unsigned rxB1 = (unsigned)__shfl_xor((int)(h ? d21 : d31), 32); \
      unsigned o00 = h ? d10 : d00, o01 = h ? d11 : d01; \
      unsigned o10 = h ? d30 : d20, o11 = h ? d31 : d21; \
      unsigned fr0[4] = { h ? rxA0 : o00, h ? rxA1 : o01, \
                          h ? o00 : rxA0, h ? o01 : rxA1 }; \
      unsigned fr1[4] = { h ? rxB0 : o10, h ? rxB1 : o11, \
                          h ? o10 : rxB0, h ? o11 : rxB1 }; \
      f16x8 pb0, pb1; \
      __builtin_memcpy(&pb0, fr0, 16); __builtin_memcpy(&pb1, fr1, 16); \
      f16x8 vf0 = *reinterpret_cast<const f16x8*>(&Vt[cur][l31][(c)*32 + h*8]); \
      f16x8 vf1 = *reinterpret_cast<const f16x8*>(&Vt[cur][l31][(c)*32 + 16 + h*8]); \
      __builtin_amdgcn_s_setprio(1); \
      oacc = __builtin_amdgcn_mfma_f32_32x32x16_f16(vf0, pb0, oacc, 0, 0, 0); \
      oacc = __builtin_amdgcn_mfma_f32_32x32x16_f16(vf1, pb1, oacc, 0, 0, 0); \
      __builtin_amdgcn_s_setprio(0); }
    PVCHUNK(s0, 0, oaccA)
    PVCHUNK(s1, 1, oaccB)
    PVCHUNK(s2, 2, oaccA)
    PVCHUNK(s3, 3, oaccB)
    #undef PVCHUNK
    lsum += ls;

    if (kt + 128 < base + KSEG) WRITET(cur ^ 1);  // vmcnt hidden by compute
    __syncthreads();
    cur ^= 1;
  }

  // epilogue: UNNORMALIZED partial O + (m, l)
  float lt = lsum + __shfl_xor(lsum, 32);
  float* op = Opart + (((size_t)zseg * NSEQ + q0 + l31) * NH + hd) * HD;
  #pragma unroll
  for (int g = 0; g < 4; g++) {            // dims 8g+4h+{0..3}
    float4 v4 = {oaccA[4*g+0] + oaccB[4*g+0], oaccA[4*g+1] + oaccB[4*g+1],
                 oaccA[4*g+2] + oaccB[4*g+2], oaccA[4*g+3] + oaccB[4*g+3]};
    *reinterpret_cast<float4*>(op + 8*g + 4*h) = v4;
  }
  if (h == 0)
    ml[((size_t)zseg * NSEQ + q0 + l31) * NH + hd] = make_float2(m_, lt);
}

// ---------------- split-K merge: Oh = norm(sum of partials) ----------------
__global__ __launch_bounds__(256) void attn_merge(const float* __restrict__ Opart,
    const float2* __restrict__ ml, f16* __restrict__ Oh){
  int t = blockIdx.x * 256 + threadIdx.x;  // NSEQ*NH*HD/4 threads
  int n = t >> 7;                          // 128 = NH*HD/4
  int rem = t & 127;
  int h = rem >> 3, dg = rem & 7;
  float2 a = ml[((size_t)0 * NSEQ + n) * NH + h];
  float2 b = ml[((size_t)1 * NSEQ + n) * NH + h];
  float m = fmaxf(a.x, b.x);
  float c0 = __builtin_amdgcn_exp2f(a.x - m);
  float c1 = __builtin_amdgcn_exp2f(b.x - m);
  float inv = 1.f / (c0 * a.y + c1 * b.y);
  float4 o0 = *reinterpret_cast<const float4*>(
      &Opart[(((size_t)0 * NSEQ + n) * NH + h) * HD + dg * 4]);
  float4 o1 = *reinterpret_cast<const float4*>(
      &Opart[(((size_t)1 * NSEQ + n) * NH + h) * HD + dg * 4]);
  f16 ob[4] = {(f16)((c0*o0.x + c1*o1.x) * inv), (f16)((c0*o0.y + c1*o1.y) * inv),
               (f16)((c0*o0.z + c1*o1.z) * inv), (f16)((c0*o0.w + c1*o1.w) * inv)};
  uint2 u; __builtin_memcpy(&u, ob, 8);
  *reinterpret_cast<uint2*>(Oh + (size_t)n * HV + h * HD + dg * 4) = u;
}

// ------------- layernorm (dim 1, ddof=1, no eps) + f16 copy ----------------
__global__ __launch_bounds__(256) void ln_kernel(const float* in, float* out,
                                                 f16* __restrict__ outh){
  __shared__ float sm[8];
  int row = blockIdx.x, tid = threadIdx.x;
  float4 x = reinterpret_cast<const float4*>(in + (size_t)row * EMB)[tid];
  float s = x.x + x.y + x.z + x.w;
  #pragma unroll
  for (int o = 32; o > 0; o >>= 1) s += __shfl_down(s, o);
  int wid = tid >> 6, lane = tid & 63;
  if (lane == 0) sm[wid] = s;
  __syncthreads();
  float mean = (sm[0] + sm[1] + sm[2] + sm[3]) * (1.f / EMB);
  float dx = x.x - mean, dy = x.y - mean, dz = x.z - mean, dw = x.w - mean;
  float qs = dx*dx + dy*dy + dz*dz + dw*dw;
  #pragma unroll
  for (int o = 32; o > 0; o >>= 1) qs += __shfl_down(qs, o);
  if (lane == 0) sm[4 + wid] = qs;
  __syncthreads();
  float var = (sm[4] + sm[5] + sm[6] + sm[7]) * (1.f / (EMB - 1));
  float inv = rsqrtf(var);
  float4 y = {dx * inv, dy * inv, dz * inv, dw * inv};
  reinterpret_cast<float4*>(out + (size_t)row * EMB)[tid] = y;
  f16 o4[4] = {(f16)y.x, (f16)y.y, (f16)y.z, (f16)y.w};
  uint2 u; __builtin_memcpy(&u, o4, 8);
  reinterpret_cast<uint2*>(outh + (size_t)row * EMB)[tid] = u;
}

extern "C" void kernel_launch(void* const* d_in, const int* in_sizes, int n_in,
                              void* d_out, int out_size, void* d_ws, size_t ws_size,
                              hipStream_t stream)
{
  const int*   ctx   = (const int*)d_in[0];
  const float* table = (const float*)d_in[1];
  const float* pos   = (const float*)d_in[2];
  const float* Wq    = (const float*)d_in[3];
  const float* Wk    = (const float*)d_in[4];
  const float* Wv    = (const float*)d_in[5];
  const float* Wo    = (const float*)d_in[6];
  const float* W1    = (const float*)d_in[7];
  const float* b1    = (const float*)d_in[8];
  const float* W2    = (const float*)d_in[9];
  const float* b2    = (const float*)d_in[10];

  float* z = (float*)d_out;                 // residual stream f32 [N][E]

  char* ws = (char*)d_ws;
  const size_t MB = 1u << 20;
  // ws layout (52 MB):
  //  [0,16)   an    f32 [N][E]      } Opart f32 [2][N][H][32] = 16MB aliases
  //  [16,24)  anh   f16 [N][E]      } [0,16); ml [16,17). Both dead during
  //  [24,32)  zh    f16 [N][E]        the attention window (an/anh written
  //  [32,44)  qkvh  f16 [N][1536]     by ln AFTER Wo-GEMM).
  //  [44,48)  Oh    f16 [N][512]
  //  [48,52)  wbuf  f16
  float*  an    = (float*)(ws);
  f16*    anh   = (f16*)  (ws + 16 * MB);
  f16*    zh    = (f16*)  (ws + 24 * MB);
  f16*    qkvh  = (f16*)  (ws + 32 * MB);
  f16*    Oh    = (f16*)  (ws + 44 * MB);
  f16*    h1h   = (f16*)  (ws + 32 * MB);
  f16*    wbuf  = (f16*)  (ws + 48 * MB);
  float*  Opart = (float*)(ws);
  float2* mlb   = (float2*)(ws + 16 * MB);

  embed_kernel<<<NSEQ * EMB / 4 / 256, 256, 0, stream>>>(ctx, table, pos, z, zh);

  for (int l = 0; l < NL; l++) {
    const float* wq  = Wq + (size_t)l * NH * EMB * HD;
    const float* wk  = Wk + (size_t)l * NH * EMB * HD;
    const float* wv  = Wv + (size_t)l * NH * EMB * HD;
    const float* wo  = Wo + (size_t)l * HV * EMB;
    const float* w1  = W1 + (size_t)l * EMB * FF;
    const float* bb1 = b1 + (size_t)l * FF;
    const float* w2  = W2 + (size_t)l * FF * EMB;
    const float* bb2 = b2 + (size_t)l * EMB;

    // qkvT rows: [0,512)=Q, [512,1024)=K, [1024,1536)=V (fused 3-in-1)
    convT3_kernel<<<dim3(EMB/32, 1, 48), 256, 0, stream>>>(wq, wk, wv, wbuf);
    gemm_mfma<f16><<<dim3(QKVW/128, NSEQ/128), 256, 0, stream>>>(
        zh, wbuf, qkvh, nullptr, nullptr, EMB, QKVW, 0);

    attn_mfma<<<dim3(NSEQ/128, NH, 2), 256, 0, stream>>>(qkvh, Opart, mlb);
    attn_merge<<<NSEQ * NH * HD / 4 / 256, 256, 0, stream>>>(Opart, mlb, Oh);

    // z += Oh @ Wo : WoT [1024][512]
    convT_kernel<<<dim3(HV/32, EMB/32, 1), 256, 0, stream>>>(
        wo, wbuf, HV, EMB, 0, 0);
    gemm_mfma<float><<<dim3(EMB/128, NSEQ/128), 256, 0, stream>>>(
        Oh, wbuf, z, nullptr, z, HV, EMB, 0);
    ln_kernel<<<NSEQ, 256, 0, stream>>>(z, an, anh);

    // h1 = leaky(an @ W1 + b1) : W1T [2048][1024]
    convT_kernel<<<dim3(EMB/32, FF/32, 1), 256, 0, stream>>>(
        w1, wbuf, EMB, FF, 0, 0);
    gemm_mfma<f16><<<dim3(FF/128, NSEQ/128), 256, 0, stream>>>(
        anh, wbuf, h1h, bb1, nullptr, EMB, FF, 1);
    // z = h1 @ W2 + b2 + an : W2T [1024][2048]
    convT_kernel<<<dim3(FF/32, EMB/32, 1), 256, 0, stream>>>(
        w2, wbuf, FF, EMB, 0, 0);
    gemm_mfma<float><<<dim3(EMB/128, NSEQ/128), 256, 0, stream>>>(
        h1h, wbuf, z, bb2, an, FF, EMB, 0);
    ln_kernel<<<NSEQ, 256, 0, stream>>>(z, z, zh);
  }
}